// Round 3
// baseline (79.679 us; speedup 1.0000x reference)
//
#include <hip/hip_runtime.h>
#include <hip/hip_bf16.h>
#include <math.h>

#define NFREQ 1024      // N_FFT//2
#define NMELS 256
#define NNOTES 82
#define KPAD  96        // K padded to multiple of 32 for mfma 16x16x32
#define KMAXH 400

typedef __attribute__((ext_vector_type(8))) short bf16x8;
typedef __attribute__((ext_vector_type(4))) float f32x4;

__device__ inline unsigned short f2bf(float x) {
    union { float f; unsigned int u; } c; c.f = x;
    unsigned int r = c.u + 0x7FFFu + ((c.u >> 16) & 1u);   // round-to-nearest-even
    return (unsigned short)(r >> 16);
}
__device__ inline float bf2f(unsigned short h) {
    union { unsigned int u; float f; } c; c.u = ((unsigned int)h) << 16; return c.f;
}

// ------------- Kernel AB (merged): harmonic cols (LDS) -> mel -> log -> split ---
__device__ inline double mel_to_hz_d(double m) {
    const double logstep = 0.06875177742094911;           // log(6.4)/27
    return (m >= 15.0) ? 1000.0 * exp(logstep * (m - 15.0)) : m * (200.0 / 3.0);
}

__global__ __launch_bounds__(256) void harm_prep(
    const float* __restrict__ omega,
    const float* __restrict__ stdv,
    const float* __restrict__ mask,
    unsigned short* __restrict__ wThi,
    unsigned short* __restrict__ wTlo)
{
    int n   = blockIdx.x;            // 0..95 (82..95 = K-pad rows)
    int tid = threadIdx.x;
    if (n >= NNOTES) {               // uniform per block: zero the pad column
        wThi[tid * KPAD + n] = 0;
        wTlo[tid * KPAD + n] = 0;
        return;
    }
    __shared__ float cols[NFREQ];

    // phase 1: cols[fi] = sum_k omega*mask*gauss for this note
    float f0 = 27.5f * exp2f((float)n / 12.0f);
    for (int fi = tid; fi < NFREQ; fi += 256) {
        float f = 11025.0f * (float)fi / 1023.0f;
        const float RAD = 80.0f;                           // 16*sigma at sigma=5
        int klo = (int)ceilf((f - RAD) / f0);
        int khi = (int)floorf((f + RAD) / f0);
        if (klo < 1) klo = 1;
        if (khi > KMAXH) khi = KMAXH;
        float acc = 0.0f;
        for (int k = klo; k <= khi; ++k) {
            int idx = n * KMAXH + (k - 1);
            float mk = mask[idx];
            if (mk == 0.0f) continue;
            float c = f0 * (float)k;
            float s = stdv[idx];
            float d = (f - c) / s;
            float e = 0.5f * d * d;
            if (e > 90.0f) continue;
            acc += omega[idx] * mk * expf(-e);
        }
        cols[fi] = acc;
    }
    __syncthreads();

    // phase 2: mel triangle m = tid over LDS cols, log-compress, bf16 split
    int m = tid;
    const double logstep = 0.06875177742094911;
    const double mel_max = 15.0 + log(11.025) / logstep;  // hz_to_mel(11025)
    double mf0 = mel_to_hz_d(mel_max * (double)m       / 257.0);
    double mf1 = mel_to_hz_d(mel_max * (double)(m + 1) / 257.0);
    double mf2 = mel_to_hz_d(mel_max * (double)(m + 2) / 257.0);
    double inv_lo = 1.0 / (mf1 - mf0);
    double inv_hi = 1.0 / (mf2 - mf1);
    double enorm  = 2.0 / (mf2 - mf0);
    int lo = (int)floor(mf0 * (1024.0 / 11025.0)) - 1;
    int hi = (int)ceil (mf2 * (1024.0 / 11025.0)) + 1;
    if (lo < 0) lo = 0;
    if (hi > 1023) hi = 1023;
    double acc = 0.0;
    for (int fi = lo; fi <= hi; ++fi) {
        double ff = 11025.0 * (double)(fi + 1) / 1024.0;
        double lower = (ff - mf0) * inv_lo;
        double upper = (mf2 - ff) * inv_hi;
        double wt = fmin(lower, upper);
        wt = fmax(0.0, wt) * enorm;
        acc += wt * (double)cols[fi];
    }
    float spec = (float)acc;
    const float X_MIN = -13.815510557964274f;             // log(1e-6)
    const float X_MAX = 3.0f;
    float x = logf(spec + 1e-6f);
    x = fminf(fmaxf(x, X_MIN), X_MAX);
    float wv = (x - X_MIN) * (1.0f / (X_MAX - X_MIN));
    unsigned short h = f2bf(wv);
    wThi[m * KPAD + n] = h;
    wTlo[m * KPAD + n] = f2bf(wv - bf2f(h));
}

// ---------------- Kernel C: out = y @ w via split-bf16 MFMA ---------------------
// Block: 64 rows x 256 cols, 4 waves (each wave 64 rows x 64 cols).
// Operand-swapped MFMA (A<-wT, B<-y): D holds 4 consecutive out-cols per lane,
// so the epilogue is 16 coalesced global_store_dwordx4 instead of 64 scalars.
__global__ __launch_bounds__(256) void harm_gemm(
    const float* __restrict__ y,
    const unsigned short* __restrict__ wThi,
    const unsigned short* __restrict__ wTlo,
    float* __restrict__ out)
{
    __shared__ unsigned short yhi[64][104];   // 13.3 KB
    __shared__ unsigned short ylo[64][104];   // 13.3 KB
    int tid = threadIdx.x;
    int m0 = blockIdx.x * 64;

    // ---- stage y tile, split f32 -> bf16 hi + lo ----
    int srow = tid >> 2, sch = tid & 3;       // 4 threads per row
    const float* yr = y + (size_t)(m0 + srow) * NNOTES;
    for (int s = sch; s < 41; s += 4) {       // 41 float2 per row (82 floats)
        float2 v;
        v.x = __builtin_nontemporal_load(yr + 2 * s);
        v.y = __builtin_nontemporal_load(yr + 2 * s + 1);
        unsigned short h0 = f2bf(v.x), h1 = f2bf(v.y);
        unsigned short l0 = f2bf(v.x - bf2f(h0)), l1 = f2bf(v.y - bf2f(h1));
        *(ushort2*)&yhi[srow][2 * s] = make_ushort2(h0, h1);
        *(ushort2*)&ylo[srow][2 * s] = make_ushort2(l0, l1);
    }
    for (int kk = NNOTES + sch; kk < KPAD; kk += 4) {     // zero K pad 82..95
        yhi[srow][kk] = 0; ylo[srow][kk] = 0;
    }
    __syncthreads();

    int lane = tid & 63;
    int wid  = tid >> 6;
    int r16  = lane & 15;
    int g4   = lane >> 4;
    int c0   = wid * 64;

    f32x4 acc[4][4];
    #pragma unroll
    for (int i = 0; i < 4; ++i)
        #pragma unroll
        for (int c = 0; c < 4; ++c) acc[i][c] = (f32x4){0.f, 0.f, 0.f, 0.f};

    #pragma unroll
    for (int kb = 0; kb < 3; ++kb) {
        int kof = kb * 32 + g4 * 8;
        bf16x8 bh[4], bl[4], ah[4], al[4];
        #pragma unroll
        for (int c = 0; c < 4; ++c) {
            size_t off = (size_t)(c0 + c * 16 + r16) * KPAD + kof;
            bh[c] = *(const bf16x8*)(wThi + off);
            bl[c] = *(const bf16x8*)(wTlo + off);
        }
        #pragma unroll
        for (int i = 0; i < 4; ++i) {
            ah[i] = *(const bf16x8*)&yhi[i * 16 + r16][kof];
            al[i] = *(const bf16x8*)&ylo[i * 16 + r16][kof];
        }
        // swapped operands: A = w fragment, B = y fragment  ->  D = block-C^T layout
        #pragma unroll
        for (int i = 0; i < 4; ++i)
            #pragma unroll
            for (int c = 0; c < 4; ++c) {
                acc[i][c] = __builtin_amdgcn_mfma_f32_16x16x32_bf16(bh[c], ah[i], acc[i][c], 0, 0, 0);
                acc[i][c] = __builtin_amdgcn_mfma_f32_16x16x32_bf16(bl[c], ah[i], acc[i][c], 0, 0, 0);
                acc[i][c] = __builtin_amdgcn_mfma_f32_16x16x32_bf16(bh[c], al[i], acc[i][c], 0, 0, 0);
            }
    }

    // ---- write C: lane holds rows m0+i*16+r16, cols c0+c*16+g4*4 .. +3 ----
    #pragma unroll
    for (int i = 0; i < 4; ++i) {
        float* orow = out + (size_t)(m0 + i * 16 + r16) * NMELS + c0 + g4 * 4;
        #pragma unroll
        for (int c = 0; c < 4; ++c)
            __builtin_nontemporal_store(acc[i][c], (f32x4*)(orow + c * 16));
    }
}

extern "C" void kernel_launch(void* const* d_in, const int* in_sizes, int n_in,
                              void* d_out, int out_size, void* d_ws, size_t ws_size,
                              hipStream_t stream) {
    const float* y     = (const float*)d_in[0];
    const float* omega = (const float*)d_in[1];
    const float* stdv  = (const float*)d_in[2];
    const float* mask  = (const float*)d_in[3];
    float* out = (float*)d_out;

    unsigned short* wThi = (unsigned short*)d_ws;
    unsigned short* wTlo = wThi + NMELS * KPAD;

    int R = in_sizes[0] / NNOTES;                               // 131072 rows

    harm_prep<<<KPAD, 256, 0, stream>>>(omega, stdv, mask, wThi, wTlo);
    harm_gemm<<<R / 64, 256, 0, stream>>>(y, wThi, wTlo, out);
}

// Round 4
// 59.733 us; speedup vs baseline: 1.3339x; 1.3339x over previous
//
#include <hip/hip_runtime.h>
#include <hip/hip_bf16.h>
#include <math.h>

#define NFREQ 1024      // N_FFT//2
#define NMELS 256
#define NNOTES 82
#define KPAD  96        // K padded to multiple of 32 for mfma 16x16x32
#define KMAXH 400

typedef __attribute__((ext_vector_type(8))) short bf16x8;
typedef __attribute__((ext_vector_type(4))) float f32x4;

__device__ inline unsigned short f2bf(float x) {
    union { float f; unsigned int u; } c; c.f = x;
    unsigned int r = c.u + 0x7FFFu + ((c.u >> 16) & 1u);   // round-to-nearest-even
    return (unsigned short)(r >> 16);
}
__device__ inline float bf2f(unsigned short h) {
    union { unsigned int u; float f; } c; c.u = ((unsigned int)h) << 16; return c.f;
}

// ------------- Kernel AB (merged): harmonic cols (LDS) -> mel -> log -> split ---
__device__ inline double mel_to_hz_d(double m) {
    const double logstep = 0.06875177742094911;           // log(6.4)/27
    return (m >= 15.0) ? 1000.0 * exp(logstep * (m - 15.0)) : m * (200.0 / 3.0);
}

__global__ __launch_bounds__(256) void harm_prep(
    const float* __restrict__ omega,
    const float* __restrict__ stdv,
    const float* __restrict__ mask,
    unsigned short* __restrict__ wThi,
    unsigned short* __restrict__ wTlo)
{
    int n   = blockIdx.x;            // 0..95 (82..95 = K-pad rows)
    int tid = threadIdx.x;
    if (n >= NNOTES) {               // uniform per block: zero the pad column
        wThi[tid * KPAD + n] = 0;
        wTlo[tid * KPAD + n] = 0;
        return;
    }
    __shared__ float cols[NFREQ];

    // phase 1: cols[fi] = sum_k omega*mask*gauss for this note
    float f0 = 27.5f * exp2f((float)n / 12.0f);
    for (int fi = tid; fi < NFREQ; fi += 256) {
        float f = 11025.0f * (float)fi / 1023.0f;
        const float RAD = 80.0f;                           // 16*sigma at sigma=5
        int klo = (int)ceilf((f - RAD) / f0);
        int khi = (int)floorf((f + RAD) / f0);
        if (klo < 1) klo = 1;
        if (khi > KMAXH) khi = KMAXH;
        float acc = 0.0f;
        for (int k = klo; k <= khi; ++k) {
            int idx = n * KMAXH + (k - 1);
            float mk = mask[idx];
            if (mk == 0.0f) continue;
            float c = f0 * (float)k;
            float s = stdv[idx];
            float d = (f - c) / s;
            float e = 0.5f * d * d;
            if (e > 90.0f) continue;
            acc += omega[idx] * mk * expf(-e);
        }
        cols[fi] = acc;
    }
    __syncthreads();

    // phase 2: mel triangle m = tid over LDS cols, log-compress, bf16 split
    int m = tid;
    const double logstep = 0.06875177742094911;
    const double mel_max = 15.0 + log(11.025) / logstep;  // hz_to_mel(11025)
    double mf0 = mel_to_hz_d(mel_max * (double)m       / 257.0);
    double mf1 = mel_to_hz_d(mel_max * (double)(m + 1) / 257.0);
    double mf2 = mel_to_hz_d(mel_max * (double)(m + 2) / 257.0);
    double inv_lo = 1.0 / (mf1 - mf0);
    double inv_hi = 1.0 / (mf2 - mf1);
    double enorm  = 2.0 / (mf2 - mf0);
    int lo = (int)floor(mf0 * (1024.0 / 11025.0)) - 1;
    int hi = (int)ceil (mf2 * (1024.0 / 11025.0)) + 1;
    if (lo < 0) lo = 0;
    if (hi > 1023) hi = 1023;
    double acc = 0.0;
    for (int fi = lo; fi <= hi; ++fi) {
        double ff = 11025.0 * (double)(fi + 1) / 1024.0;
        double lower = (ff - mf0) * inv_lo;
        double upper = (mf2 - ff) * inv_hi;
        double wt = fmin(lower, upper);
        wt = fmax(0.0, wt) * enorm;
        acc += wt * (double)cols[fi];
    }
    float spec = (float)acc;
    const float X_MIN = -13.815510557964274f;             // log(1e-6)
    const float X_MAX = 3.0f;
    float x = logf(spec + 1e-6f);
    x = fminf(fmaxf(x, X_MIN), X_MAX);
    float wv = (x - X_MIN) * (1.0f / (X_MAX - X_MIN));
    unsigned short h = f2bf(wv);
    wThi[m * KPAD + n] = h;
    wTlo[m * KPAD + n] = f2bf(wv - bf2f(h));
}

// ---------------- Kernel C: out = y @ w via split-bf16 MFMA ---------------------
// Block: 64 rows x 256 cols, 4 waves (each wave 64 rows x 64 cols).
// Swapped-operand MFMA (A<-wT, B<-y): lane holds 4 consecutive out-cols per reg.
// Epilogue transposes through LDS so every store instruction writes 4 KB of
// fully-contiguous output (each wave = one whole 1024B row).
#define EPS_LD 260                       // f32 row stride in epilogue LDS (pad 4)
__global__ __launch_bounds__(256) void harm_gemm(
    const float* __restrict__ y,
    const unsigned short* __restrict__ wThi,
    const unsigned short* __restrict__ wTlo,
    float* __restrict__ out)
{
    // union: y staging (26.6 KB) then epilogue transpose buffer (33.3 KB)
    __shared__ __align__(16) unsigned char smem[32 * EPS_LD * 4];
    unsigned short (*yhi)[104] = (unsigned short (*)[104])smem;
    unsigned short (*ylo)[104] = (unsigned short (*)[104])(smem + 64 * 104 * 2);
    float* eps = (float*)smem;

    int tid = threadIdx.x;
    int m0 = blockIdx.x * 64;

    // ---- stage y tile, split f32 -> bf16 hi + lo ----
    int srow = tid >> 2, sch = tid & 3;       // 4 threads per row
    const float* yr = y + (size_t)(m0 + srow) * NNOTES;
    for (int s = sch; s < 41; s += 4) {       // 41 float2 per row (82 floats)
        float2 v = *(const float2*)(yr + 2 * s);
        unsigned short h0 = f2bf(v.x), h1 = f2bf(v.y);
        unsigned short l0 = f2bf(v.x - bf2f(h0)), l1 = f2bf(v.y - bf2f(h1));
        *(ushort2*)&yhi[srow][2 * s] = make_ushort2(h0, h1);
        *(ushort2*)&ylo[srow][2 * s] = make_ushort2(l0, l1);
    }
    for (int kk = NNOTES + sch; kk < KPAD; kk += 4) {     // zero K pad 82..95
        yhi[srow][kk] = 0; ylo[srow][kk] = 0;
    }
    __syncthreads();

    int lane = tid & 63;
    int wid  = tid >> 6;
    int r16  = lane & 15;
    int g4   = lane >> 4;
    int c0   = wid * 64;

    f32x4 acc[4][4];
    #pragma unroll
    for (int i = 0; i < 4; ++i)
        #pragma unroll
        for (int c = 0; c < 4; ++c) acc[i][c] = (f32x4){0.f, 0.f, 0.f, 0.f};

    #pragma unroll
    for (int kb = 0; kb < 3; ++kb) {
        int kof = kb * 32 + g4 * 8;
        bf16x8 bh[4], bl[4], ah[4], al[4];
        #pragma unroll
        for (int c = 0; c < 4; ++c) {
            size_t off = (size_t)(c0 + c * 16 + r16) * KPAD + kof;
            bh[c] = *(const bf16x8*)(wThi + off);
            bl[c] = *(const bf16x8*)(wTlo + off);
        }
        #pragma unroll
        for (int i = 0; i < 4; ++i) {
            ah[i] = *(const bf16x8*)&yhi[i * 16 + r16][kof];
            al[i] = *(const bf16x8*)&ylo[i * 16 + r16][kof];
        }
        // swapped operands: A = w fragment, B = y fragment
        // -> lane holds out[row = i*16+r16][col = c0 + c*16 + g4*4 + reg]
        #pragma unroll
        for (int i = 0; i < 4; ++i)
            #pragma unroll
            for (int c = 0; c < 4; ++c) {
                acc[i][c] = __builtin_amdgcn_mfma_f32_16x16x32_bf16(bh[c], ah[i], acc[i][c], 0, 0, 0);
                acc[i][c] = __builtin_amdgcn_mfma_f32_16x16x32_bf16(bl[c], ah[i], acc[i][c], 0, 0, 0);
                acc[i][c] = __builtin_amdgcn_mfma_f32_16x16x32_bf16(bh[c], al[i], acc[i][c], 0, 0, 0);
            }
    }

    // ---- epilogue: transpose 32-row halves through LDS, store coalesced ----
    #pragma unroll
    for (int h = 0; h < 2; ++h) {
        __syncthreads();                      // LDS reuse / prev chunk done
        #pragma unroll
        for (int ii = 0; ii < 2; ++ii) {
            int i = 2 * h + ii;
            int row32 = ii * 16 + r16;
            #pragma unroll
            for (int c = 0; c < 4; ++c)
                *(f32x4*)&eps[row32 * EPS_LD + c0 + c * 16 + g4 * 4] = acc[i][c];
        }
        __syncthreads();
        int rb = tid >> 6;                    // 0..3
        int ch = tid & 63;                    // 0..63 col chunks of 4 floats
        #pragma unroll
        for (int p = 0; p < 8; ++p) {
            int r = p * 4 + rb;
            f32x4 v = *(const f32x4*)&eps[r * EPS_LD + ch * 4];
            *(f32x4*)(out + (size_t)(m0 + h * 32 + r) * NMELS + ch * 4) = v;
        }
    }
}

extern "C" void kernel_launch(void* const* d_in, const int* in_sizes, int n_in,
                              void* d_out, int out_size, void* d_ws, size_t ws_size,
                              hipStream_t stream) {
    const float* y     = (const float*)d_in[0];
    const float* omega = (const float*)d_in[1];
    const float* stdv  = (const float*)d_in[2];
    const float* mask  = (const float*)d_in[3];
    float* out = (float*)d_out;

    unsigned short* wThi = (unsigned short*)d_ws;
    unsigned short* wTlo = wThi + NMELS * KPAD;

    int R = in_sizes[0] / NNOTES;                               // 131072 rows

    harm_prep<<<KPAD, 256, 0, stream>>>(omega, stdv, mask, wThi, wTlo);
    harm_gemm<<<R / 64, 256, 0, stream>>>(y, wThi, wTlo, out);
}

// Round 5
// 54.730 us; speedup vs baseline: 1.4559x; 1.0914x over previous
//
#include <hip/hip_runtime.h>
#include <hip/hip_bf16.h>
#include <math.h>

#define NFREQ 1024      // N_FFT//2
#define NMELS 256
#define NNOTES 82
#define KPAD  96        // K padded to multiple of 32 for mfma 16x16x32
#define KMAXH 400

typedef __attribute__((ext_vector_type(8))) short bf16x8;
typedef __attribute__((ext_vector_type(4))) float f32x4;

__device__ inline unsigned short f2bf(float x) {
    union { float f; unsigned int u; } c; c.f = x;
    unsigned int r = c.u + 0x7FFFu + ((c.u >> 16) & 1u);   // round-to-nearest-even
    return (unsigned short)(r >> 16);
}

// ------------- Kernel AB (merged): harmonic cols (LDS) -> mel -> log -> bf16 ----
__device__ inline double mel_to_hz_d(double m) {
    const double logstep = 0.06875177742094911;           // log(6.4)/27
    return (m >= 15.0) ? 1000.0 * exp(logstep * (m - 15.0)) : m * (200.0 / 3.0);
}

__global__ __launch_bounds__(256) void harm_prep(
    const float* __restrict__ omega,
    const float* __restrict__ stdv,
    const float* __restrict__ mask,
    unsigned short* __restrict__ wT)
{
    int n   = blockIdx.x;            // 0..95 (82..95 = K-pad rows)
    int tid = threadIdx.x;
    if (n >= NNOTES) {               // uniform per block: zero the pad column
        wT[tid * KPAD + n] = 0;
        return;
    }
    __shared__ float cols[NFREQ];

    // phase 1: cols[fi] = sum_k omega*mask*gauss for this note
    float f0 = 27.5f * exp2f((float)n / 12.0f);
    for (int fi = tid; fi < NFREQ; fi += 256) {
        float f = 11025.0f * (float)fi / 1023.0f;
        const float RAD = 80.0f;                           // 16*sigma at sigma=5
        int klo = (int)ceilf((f - RAD) / f0);
        int khi = (int)floorf((f + RAD) / f0);
        if (klo < 1) klo = 1;
        if (khi > KMAXH) khi = KMAXH;
        float acc = 0.0f;
        for (int k = klo; k <= khi; ++k) {
            int idx = n * KMAXH + (k - 1);
            float mk = mask[idx];
            if (mk == 0.0f) continue;
            float c = f0 * (float)k;
            float s = stdv[idx];
            float d = (f - c) / s;
            float e = 0.5f * d * d;
            if (e > 90.0f) continue;
            acc += omega[idx] * mk * expf(-e);
        }
        cols[fi] = acc;
    }
    __syncthreads();

    // phase 2: mel triangle m = tid over LDS cols, log-compress, bf16
    int m = tid;
    const double logstep = 0.06875177742094911;
    const double mel_max = 15.0 + log(11.025) / logstep;  // hz_to_mel(11025)
    double mf0 = mel_to_hz_d(mel_max * (double)m       / 257.0);
    double mf1 = mel_to_hz_d(mel_max * (double)(m + 1) / 257.0);
    double mf2 = mel_to_hz_d(mel_max * (double)(m + 2) / 257.0);
    double inv_lo = 1.0 / (mf1 - mf0);
    double inv_hi = 1.0 / (mf2 - mf1);
    double enorm  = 2.0 / (mf2 - mf0);
    int lo = (int)floor(mf0 * (1024.0 / 11025.0)) - 1;
    int hi = (int)ceil (mf2 * (1024.0 / 11025.0)) + 1;
    if (lo < 0) lo = 0;
    if (hi > 1023) hi = 1023;
    double acc = 0.0;
    for (int fi = lo; fi <= hi; ++fi) {
        double ff = 11025.0 * (double)(fi + 1) / 1024.0;
        double lower = (ff - mf0) * inv_lo;
        double upper = (mf2 - ff) * inv_hi;
        double wt = fmin(lower, upper);
        wt = fmax(0.0, wt) * enorm;
        acc += wt * (double)cols[fi];
    }
    float spec = (float)acc;
    const float X_MIN = -13.815510557964274f;             // log(1e-6)
    const float X_MAX = 3.0f;
    float x = logf(spec + 1e-6f);
    x = fminf(fmaxf(x, X_MIN), X_MAX);
    float wv = (x - X_MIN) * (1.0f / (X_MAX - X_MIN));
    wT[m * KPAD + n] = f2bf(wv);
}

// ---------------- Kernel C: out = y @ w via single-bf16 MFMA --------------------
// Block: 64 rows x 256 cols, 4 waves (each wave 64 rows x 64 cols).
// Swapped-operand MFMA (A<-wT, B<-y): lane holds 4 consecutive out-cols per reg
// -> f32x4 direct stores (64B segments). Staging: float2 -> v_cvt_pk_bf16_f32
// -> ds_write_b32 (single-bf16; no hi/lo split).
__global__ __launch_bounds__(256) void harm_gemm(
    const float* __restrict__ y,
    const unsigned short* __restrict__ wT,
    float* __restrict__ out)
{
    __shared__ unsigned short ybf[64][104];   // 13.3 KB
    int tid = threadIdx.x;
    int m0 = blockIdx.x * 64;

    // ---- stage y tile f32 -> bf16 ----
    int srow = tid >> 2, sch = tid & 3;       // 4 threads per row
    const float* yr = y + (size_t)(m0 + srow) * NNOTES;
    for (int s = sch; s < 41; s += 4) {       // 41 float2 per row (82 floats)
        float2 v = *(const float2*)(yr + 2 * s);
        unsigned int packed;
        asm("v_cvt_pk_bf16_f32 %0, %1, %2" : "=v"(packed) : "v"(v.x), "v"(v.y));
        *(unsigned int*)&ybf[srow][2 * s] = packed;
    }
    #pragma unroll
    for (int p = sch; p < 7; p += 4)          // zero K pad 82..95 (7 pairs)
        *(unsigned int*)&ybf[srow][82 + 2 * p] = 0u;
    __syncthreads();

    int lane = tid & 63;
    int wid  = tid >> 6;
    int r16  = lane & 15;
    int g4   = lane >> 4;
    int c0   = wid * 64;

    f32x4 acc[4][4];
    #pragma unroll
    for (int i = 0; i < 4; ++i)
        #pragma unroll
        for (int c = 0; c < 4; ++c) acc[i][c] = (f32x4){0.f, 0.f, 0.f, 0.f};

    #pragma unroll
    for (int kb = 0; kb < 3; ++kb) {
        int kof = kb * 32 + g4 * 8;
        bf16x8 bw[4], ay[4];
        #pragma unroll
        for (int c = 0; c < 4; ++c)
            bw[c] = *(const bf16x8*)(wT + (size_t)(c0 + c * 16 + r16) * KPAD + kof);
        #pragma unroll
        for (int i = 0; i < 4; ++i)
            ay[i] = *(const bf16x8*)&ybf[i * 16 + r16][kof];
        // swapped operands: A = w fragment, B = y fragment
        // -> lane holds out[row = m0+i*16+r16][col = c0 + c*16 + g4*4 + reg]
        #pragma unroll
        for (int i = 0; i < 4; ++i)
            #pragma unroll
            for (int c = 0; c < 4; ++c)
                acc[i][c] = __builtin_amdgcn_mfma_f32_16x16x32_bf16(bw[c], ay[i], acc[i][c], 0, 0, 0);
    }

    // ---- write C: 16 f32x4 stores per lane, 64B segments ----
    #pragma unroll
    for (int i = 0; i < 4; ++i) {
        float* orow = out + (size_t)(m0 + i * 16 + r16) * NMELS + c0 + g4 * 4;
        #pragma unroll
        for (int c = 0; c < 4; ++c)
            *(f32x4*)(orow + c * 16) = acc[i][c];
    }
}

extern "C" void kernel_launch(void* const* d_in, const int* in_sizes, int n_in,
                              void* d_out, int out_size, void* d_ws, size_t ws_size,
                              hipStream_t stream) {
    const float* y     = (const float*)d_in[0];
    const float* omega = (const float*)d_in[1];
    const float* stdv  = (const float*)d_in[2];
    const float* mask  = (const float*)d_in[3];
    float* out = (float*)d_out;

    unsigned short* wT = (unsigned short*)d_ws;           // 256*96 bf16

    int R = in_sizes[0] / NNOTES;                         // 131072 rows

    harm_prep<<<KPAD, 256, 0, stream>>>(omega, stdv, mask, wT);
    harm_gemm<<<R / 64, 256, 0, stream>>>(y, wT, out);
}

// Round 6
// 49.298 us; speedup vs baseline: 1.6163x; 1.1102x over previous
//
#include <hip/hip_runtime.h>
#include <hip/hip_bf16.h>
#include <math.h>

#define NFREQ 1024      // N_FFT//2
#define NMELS 256
#define NNOTES 82
#define KPAD  96        // K padded to multiple of 32 for mfma 16x16x32
#define KMAXH 400

typedef __attribute__((ext_vector_type(8))) short bf16x8;
typedef __attribute__((ext_vector_type(4))) float f32x4;

__device__ inline unsigned short f2bf(float x) {
    union { float f; unsigned int u; } c; c.f = x;
    unsigned int r = c.u + 0x7FFFu + ((c.u >> 16) & 1u);   // round-to-nearest-even
    return (unsigned short)(r >> 16);
}

// ------------- Kernel AB (merged): harmonic cols (LDS) -> mel -> log -> bf16 ----
__device__ inline double mel_to_hz_d(double m) {
    const double logstep = 0.06875177742094911;           // log(6.4)/27
    return (m >= 15.0) ? 1000.0 * exp(logstep * (m - 15.0)) : m * (200.0 / 3.0);
}

__global__ __launch_bounds__(256) void harm_prep(
    const float* __restrict__ omega,
    const float* __restrict__ stdv,
    const float* __restrict__ mask,
    unsigned short* __restrict__ wT)
{
    int n   = blockIdx.x;            // 0..95 (82..95 = K-pad rows)
    int tid = threadIdx.x;
    if (n >= NNOTES) {               // uniform per block: zero the pad column
        wT[tid * KPAD + n] = 0;
        return;
    }
    __shared__ float cols[NFREQ];

    // phase 1: cols[fi] = sum_k omega*mask*gauss for this note
    float f0 = 27.5f * exp2f((float)n / 12.0f);
    for (int fi = tid; fi < NFREQ; fi += 256) {
        float f = 11025.0f * (float)fi / 1023.0f;
        const float RAD = 80.0f;                           // 16*sigma at sigma=5
        int klo = (int)ceilf((f - RAD) / f0);
        int khi = (int)floorf((f + RAD) / f0);
        if (klo < 1) klo = 1;
        if (khi > KMAXH) khi = KMAXH;
        float acc = 0.0f;
        for (int k = klo; k <= khi; ++k) {
            int idx = n * KMAXH + (k - 1);
            float mk = mask[idx];
            if (mk == 0.0f) continue;
            float c = f0 * (float)k;
            float s = stdv[idx];
            float d = (f - c) / s;
            float e = 0.5f * d * d;
            if (e > 90.0f) continue;
            acc += omega[idx] * mk * expf(-e);
        }
        cols[fi] = acc;
    }
    __syncthreads();

    // phase 2: mel triangle m = tid over LDS cols, log-compress, bf16
    int m = tid;
    const double logstep = 0.06875177742094911;
    const double mel_max = 15.0 + log(11.025) / logstep;  // hz_to_mel(11025)
    double mf0 = mel_to_hz_d(mel_max * (double)m       / 257.0);
    double mf1 = mel_to_hz_d(mel_max * (double)(m + 1) / 257.0);
    double mf2 = mel_to_hz_d(mel_max * (double)(m + 2) / 257.0);
    double inv_lo = 1.0 / (mf1 - mf0);
    double inv_hi = 1.0 / (mf2 - mf1);
    double enorm  = 2.0 / (mf2 - mf0);
    int lo = (int)floor(mf0 * (1024.0 / 11025.0)) - 1;
    int hi = (int)ceil (mf2 * (1024.0 / 11025.0)) + 1;
    if (lo < 0) lo = 0;
    if (hi > 1023) hi = 1023;
    double acc = 0.0;
    for (int fi = lo; fi <= hi; ++fi) {
        double ff = 11025.0 * (double)(fi + 1) / 1024.0;
        double lower = (ff - mf0) * inv_lo;
        double upper = (mf2 - ff) * inv_hi;
        double wt = fmin(lower, upper);
        wt = fmax(0.0, wt) * enorm;
        acc += wt * (double)cols[fi];
    }
    float spec = (float)acc;
    const float X_MIN = -13.815510557964274f;             // log(1e-6)
    const float X_MAX = 3.0f;
    float x = logf(spec + 1e-6f);
    x = fminf(fmaxf(x, X_MIN), X_MAX);
    float wv = (x - X_MIN) * (1.0f / (X_MAX - X_MIN));
    wT[m * KPAD + n] = f2bf(wv);
}

// ---------------- Kernel C: out = y @ w via single-bf16 MFMA --------------------
// Block: 64 rows x 256 cols, 4 waves (each wave 64 rows x 64 cols).
// Staging: the 64x82 y tile is 5248 CONTIGUOUS floats -> 6 independent float4
// loads per thread (1KB/wave-instr, 6x MLP), magic-div by 82 for (row,col),
// v_cvt_pk_bf16_f32 -> ds_write_b32. float2-granules never cross rows (82 even).
__global__ __launch_bounds__(256) void harm_gemm(
    const float* __restrict__ y,
    const unsigned short* __restrict__ wT,
    float* __restrict__ out)
{
    __shared__ unsigned short ybf[64][104];   // 13.3 KB
    int tid = threadIdx.x;
    int m0 = blockIdx.x * 64;

    // ---- stage y tile f32 -> bf16 (coalesced, deep MLP) ----
    {
        const float4* ysrc = (const float4*)(y + (size_t)m0 * NNOTES);  // 16B-aligned: 64*82*4 = 20992 B per block
        float4 v[6];
        #pragma unroll
        for (int p = 0; p < 6; ++p) {
            int j = tid + 256 * p;
            if (j < 1312) v[p] = ysrc[j];                 // 1312 = 5248/4
        }
        #pragma unroll
        for (int p = 0; p < 6; ++p) {
            int j = tid + 256 * p;
            if (j < 1312) {
                int e0 = 4 * j;                            // flat element index
                int e1 = e0 + 2;
                int r0 = (int)(((unsigned)e0 * 51151u) >> 22);   // e0/82
                int r1 = (int)(((unsigned)e1 * 51151u) >> 22);   // e1/82
                int c0e = e0 - 82 * r0;
                int c1e = e1 - 82 * r1;
                unsigned pk0, pk1;
                asm("v_cvt_pk_bf16_f32 %0, %1, %2" : "=v"(pk0) : "v"(v[p].x), "v"(v[p].y));
                asm("v_cvt_pk_bf16_f32 %0, %1, %2" : "=v"(pk1) : "v"(v[p].z), "v"(v[p].w));
                *(unsigned*)&ybf[r0][c0e] = pk0;
                *(unsigned*)&ybf[r1][c1e] = pk1;
            }
        }
        // zero K-pad cols 82..95: 64 rows x 7 u32
        for (int q = tid; q < 448; q += 256) {
            int r = (int)(((unsigned)q * 9363u) >> 16);    // q/7
            int c7 = q - 7 * r;
            *(unsigned*)&ybf[r][82 + 2 * c7] = 0u;
        }
    }
    __syncthreads();

    int lane = tid & 63;
    int wid  = tid >> 6;
    int r16  = lane & 15;
    int g4   = lane >> 4;
    int c0   = wid * 64;

    f32x4 acc[4][4];
    #pragma unroll
    for (int i = 0; i < 4; ++i)
        #pragma unroll
        for (int c = 0; c < 4; ++c) acc[i][c] = (f32x4){0.f, 0.f, 0.f, 0.f};

    #pragma unroll
    for (int kb = 0; kb < 3; ++kb) {
        int kof = kb * 32 + g4 * 8;
        bf16x8 bw[4], ay[4];
        #pragma unroll
        for (int c = 0; c < 4; ++c)
            bw[c] = *(const bf16x8*)(wT + (size_t)(c0 + c * 16 + r16) * KPAD + kof);
        #pragma unroll
        for (int i = 0; i < 4; ++i)
            ay[i] = *(const bf16x8*)&ybf[i * 16 + r16][kof];
        // swapped operands: A = w fragment, B = y fragment
        // -> lane holds out[row = m0+i*16+r16][col = c0 + c*16 + g4*4 + reg]
        #pragma unroll
        for (int i = 0; i < 4; ++i)
            #pragma unroll
            for (int c = 0; c < 4; ++c)
                acc[i][c] = __builtin_amdgcn_mfma_f32_16x16x32_bf16(bw[c], ay[i], acc[i][c], 0, 0, 0);
    }

    // ---- write C: 16 f32x4 stores per lane, 64B segments ----
    #pragma unroll
    for (int i = 0; i < 4; ++i) {
        float* orow = out + (size_t)(m0 + i * 16 + r16) * NMELS + c0 + g4 * 4;
        #pragma unroll
        for (int c = 0; c < 4; ++c)
            *(f32x4*)(orow + c * 16) = acc[i][c];
    }
}

extern "C" void kernel_launch(void* const* d_in, const int* in_sizes, int n_in,
                              void* d_out, int out_size, void* d_ws, size_t ws_size,
                              hipStream_t stream) {
    const float* y     = (const float*)d_in[0];
    const float* omega = (const float*)d_in[1];
    const float* stdv  = (const float*)d_in[2];
    const float* mask  = (const float*)d_in[3];
    float* out = (float*)d_out;

    unsigned short* wT = (unsigned short*)d_ws;           // 256*96 bf16

    int R = in_sizes[0] / NNOTES;                         // 131072 rows

    harm_prep<<<KPAD, 256, 0, stream>>>(omega, stdv, mask, wT);
    harm_gemm<<<R / 64, 256, 0, stream>>>(y, wT, out);
}

// Round 7
// 47.556 us; speedup vs baseline: 1.6755x; 1.0366x over previous
//
#include <hip/hip_runtime.h>
#include <hip/hip_bf16.h>
#include <math.h>

#define NFREQ 1024      // N_FFT//2
#define NMELS 256
#define NNOTES 82
#define KPAD  96        // K padded to multiple of 32 for mfma 16x16x32
#define KMAXH 400

typedef __attribute__((ext_vector_type(8))) short bf16x8;
typedef __attribute__((ext_vector_type(4))) float f32x4;

__device__ inline unsigned short f2bf(float x) {
    union { float f; unsigned int u; } c; c.f = x;
    unsigned int r = c.u + 0x7FFFu + ((c.u >> 16) & 1u);   // round-to-nearest-even
    return (unsigned short)(r >> 16);
}

// ------------- Kernel AB (merged): harmonic cols (LDS) -> mel -> log -> bf16 ----
__device__ inline double mel_to_hz_d(double m) {
    const double logstep = 0.06875177742094911;           // log(6.4)/27
    return (m >= 15.0) ? 1000.0 * exp(logstep * (m - 15.0)) : m * (200.0 / 3.0);
}

__global__ __launch_bounds__(256) void harm_prep(
    const float* __restrict__ omega,
    const float* __restrict__ stdv,
    const float* __restrict__ mask,
    unsigned short* __restrict__ wT)
{
    int n   = blockIdx.x;            // 0..95 (82..95 = K-pad rows)
    int tid = threadIdx.x;
    if (n >= NNOTES) {               // uniform per block: zero the pad column
        wT[tid * KPAD + n] = 0;
        return;
    }
    __shared__ float cols[NFREQ];

    // phase 1: cols[fi] = sum_k omega*mask*gauss for this note
    float f0 = 27.5f * exp2f((float)n / 12.0f);
    for (int fi = tid; fi < NFREQ; fi += 256) {
        float f = 11025.0f * (float)fi / 1023.0f;
        const float RAD = 80.0f;                           // 16*sigma at sigma=5
        int klo = (int)ceilf((f - RAD) / f0);
        int khi = (int)floorf((f + RAD) / f0);
        if (klo < 1) klo = 1;
        if (khi > KMAXH) khi = KMAXH;
        float acc = 0.0f;
        for (int k = klo; k <= khi; ++k) {
            int idx = n * KMAXH + (k - 1);
            float mk = mask[idx];
            if (mk == 0.0f) continue;
            float c = f0 * (float)k;
            float s = stdv[idx];
            float d = (f - c) / s;
            float e = 0.5f * d * d;
            if (e > 90.0f) continue;
            acc += omega[idx] * mk * expf(-e);
        }
        cols[fi] = acc;
    }
    __syncthreads();

    // phase 2: mel triangle m = tid over LDS cols, log-compress, bf16
    int m = tid;
    const double logstep = 0.06875177742094911;
    const double mel_max = 15.0 + log(11.025) / logstep;  // hz_to_mel(11025)
    double mf0 = mel_to_hz_d(mel_max * (double)m       / 257.0);
    double mf1 = mel_to_hz_d(mel_max * (double)(m + 1) / 257.0);
    double mf2 = mel_to_hz_d(mel_max * (double)(m + 2) / 257.0);
    double inv_lo = 1.0 / (mf1 - mf0);
    double inv_hi = 1.0 / (mf2 - mf1);
    double enorm  = 2.0 / (mf2 - mf0);
    int lo = (int)floor(mf0 * (1024.0 / 11025.0)) - 1;
    int hi = (int)ceil (mf2 * (1024.0 / 11025.0)) + 1;
    if (lo < 0) lo = 0;
    if (hi > 1023) hi = 1023;
    double acc = 0.0;
    for (int fi = lo; fi <= hi; ++fi) {
        double ff = 11025.0 * (double)(fi + 1) / 1024.0;
        double lower = (ff - mf0) * inv_lo;
        double upper = (mf2 - ff) * inv_hi;
        double wt = fmin(lower, upper);
        wt = fmax(0.0, wt) * enorm;
        acc += wt * (double)cols[fi];
    }
    float spec = (float)acc;
    const float X_MIN = -13.815510557964274f;             // log(1e-6)
    const float X_MAX = 3.0f;
    float x = logf(spec + 1e-6f);
    x = fminf(fmaxf(x, X_MIN), X_MAX);
    float wv = (x - X_MIN) * (1.0f / (X_MAX - X_MIN));
    wT[m * KPAD + n] = f2bf(wv);
}

// ---------------- Kernel C: out = y @ w, single-bf16 MFMA, 2-tile pipeline ------
// Block: 2 x (64 rows) x 256 cols, 4 waves. w fragments hoisted to the top
// (L2 latency hides under tile-0 staging); tile-1 y loads issued before tile-0
// compute (HBM latency hides under MFMA+stores); double-buffered LDS.

__device__ __forceinline__ void stage_load(const float* ybase, float4* v, int tid) {
    const float4* ysrc = (const float4*)ybase;            // 64*82 = 5248 floats = 1312 float4
    #pragma unroll
    for (int p = 0; p < 6; ++p) {
        int j = tid + 256 * p;
        if (j < 1312) v[p] = ysrc[j];
    }
}

__device__ __forceinline__ void stage_write(const float4* v, unsigned short (*ybf)[104], int tid) {
    #pragma unroll
    for (int p = 0; p < 6; ++p) {
        int j = tid + 256 * p;
        if (j < 1312) {
            int e0 = 4 * j;                                // flat element index
            int e1 = e0 + 2;
            int r0 = (int)(((unsigned)e0 * 51151u) >> 22); // e0/82
            int r1 = (int)(((unsigned)e1 * 51151u) >> 22); // e1/82
            int c0e = e0 - 82 * r0;
            int c1e = e1 - 82 * r1;
            unsigned pk0, pk1;
            asm("v_cvt_pk_bf16_f32 %0, %1, %2" : "=v"(pk0) : "v"(v[p].x), "v"(v[p].y));
            asm("v_cvt_pk_bf16_f32 %0, %1, %2" : "=v"(pk1) : "v"(v[p].z), "v"(v[p].w));
            *(unsigned*)&ybf[r0][c0e] = pk0;
            *(unsigned*)&ybf[r1][c1e] = pk1;
        }
    }
    // zero K-pad cols 82..95: 64 rows x 7 u32
    for (int q = tid; q < 448; q += 256) {
        int r = (int)(((unsigned)q * 9363u) >> 16);        // q/7
        int c7 = q - 7 * r;
        *(unsigned*)&ybf[r][82 + 2 * c7] = 0u;
    }
}

__device__ __forceinline__ void gemm_tile(
    const unsigned short (*ybf)[104], const bf16x8 bw[3][4],
    float* __restrict__ out, int mb, int r16, int g4, int c0)
{
    #pragma unroll
    for (int i = 0; i < 4; ++i) {
        f32x4 acc[4];
        #pragma unroll
        for (int c = 0; c < 4; ++c) acc[c] = (f32x4){0.f, 0.f, 0.f, 0.f};
        #pragma unroll
        for (int kb = 0; kb < 3; ++kb) {
            bf16x8 ay = *(const bf16x8*)&ybf[i * 16 + r16][kb * 32 + g4 * 8];
            #pragma unroll
            for (int c = 0; c < 4; ++c)
                acc[c] = __builtin_amdgcn_mfma_f32_16x16x32_bf16(bw[kb][c], ay, acc[c], 0, 0, 0);
        }
        // lane holds out[row = mb+i*16+r16][col = c0 + c*16 + g4*4 + reg]
        float* orow = out + (size_t)(mb + i * 16 + r16) * NMELS + c0 + g4 * 4;
        #pragma unroll
        for (int c = 0; c < 4; ++c)
            *(f32x4*)(orow + c * 16) = acc[c];
    }
}

__global__ __launch_bounds__(256) void harm_gemm(
    const float* __restrict__ y,
    const unsigned short* __restrict__ wT,
    float* __restrict__ out)
{
    __shared__ unsigned short ybf[2][64][104];   // 26.6 KB double buffer
    int tid  = threadIdx.x;
    int m0   = blockIdx.x * 128;
    int lane = tid & 63;
    int wid  = tid >> 6;
    int r16  = lane & 15;
    int g4   = lane >> 4;
    int c0   = wid * 64;

    // ---- w fragments first: block-invariant, latency hides under staging ----
    bf16x8 bw[3][4];
    #pragma unroll
    for (int kb = 0; kb < 3; ++kb)
        #pragma unroll
        for (int c = 0; c < 4; ++c)
            bw[kb][c] = *(const bf16x8*)(wT + (size_t)(c0 + c * 16 + r16) * KPAD + kb * 32 + g4 * 8);

    // ---- tile 0: load + stage ----
    float4 v0[6];
    stage_load(y + (size_t)m0 * NNOTES, v0, tid);
    stage_write(v0, ybf[0], tid);
    __syncthreads();

    // ---- tile 1 loads in flight during tile-0 compute ----
    float4 v1[6];
    stage_load(y + (size_t)(m0 + 64) * NNOTES, v1, tid);

    gemm_tile(ybf[0], bw, out, m0, r16, g4, c0);

    stage_write(v1, ybf[1], tid);
    __syncthreads();
    gemm_tile(ybf[1], bw, out, m0 + 64, r16, g4, c0);
}

extern "C" void kernel_launch(void* const* d_in, const int* in_sizes, int n_in,
                              void* d_out, int out_size, void* d_ws, size_t ws_size,
                              hipStream_t stream) {
    const float* y     = (const float*)d_in[0];
    const float* omega = (const float*)d_in[1];
    const float* stdv  = (const float*)d_in[2];
    const float* mask  = (const float*)d_in[3];
    float* out = (float*)d_out;

    unsigned short* wT = (unsigned short*)d_ws;           // 256*96 bf16

    int R = in_sizes[0] / NNOTES;                         // 131072 rows

    harm_prep<<<KPAD, 256, 0, stream>>>(omega, stdv, mask, wT);
    harm_gemm<<<R / 128, 256, 0, stream>>>(y, wT, out);
}